// Round 1
// baseline (255.708 us; speedup 1.0000x reference)
//
#include <hip/hip_runtime.h>
#include <hip/hip_fp16.h>
#include <stdint.h>

#define N_EDGES 200000
#define N_NODES 50000
#define BM 128
#define NT 512

typedef _Float16 f16x8 __attribute__((ext_vector_type(8)));
typedef float f32x4 __attribute__((ext_vector_type(4)));

// ---- prep_w: W -> f16, scales folded. wt[T*2048 + w*32 + kk] = f16(scale*W[k=T*32+kk][w])
__global__ void prep_w(const float* __restrict__ W0, const float* __restrict__ W1,
                       const float* __restrict__ W2, uint16_t* __restrict__ wt) {
  int o = blockIdx.x * 256 + threadIdx.x;     // 147456 total
  int T = o >> 11, r = o & 2047, w = r >> 5, kk = r & 31;
  int k = T * 32 + kk;
  const float AS = 1.0f / 48.0f;                  // 1/sqrt(2304)
  const float AV = AS * 0.57735026918962576f;     // /sqrt(3)
  const float AT = AS * 0.44721359549995794f;     // /sqrt(5)
  float val;
  if (k < 1024)      val = AS * W0[(k >> 5) * 2048 + (k & 31) * 64 + w];
  else if (k < 2048) { int k2 = k - 1024; val = AV * W1[(k2 >> 5) * 2048 + (k2 & 31) * 64 + w]; }
  else               { int k2 = k - 2048; val = AT * W2[(k2 >> 4) * 1024 + (k2 & 15) * 64 + w]; }
  __half h = __float2half(val);
  wt[o] = *reinterpret_cast<uint16_t*>(&h);
}

// ---- prep_tables: node_tensors -> TA (u-major, 296 u16/row) + TB (m-major, 216 u16/row)
__global__ void prep_tables(const float* __restrict__ nt,
                            uint16_t* __restrict__ ta, uint16_t* __restrict__ tb) {
  long long o = (long long)blockIdx.x * 256 + threadIdx.x;
  if (o >= (long long)N_NODES * 296) return;
  int node = (int)(o / 296);
  int r = (int)(o - (long long)node * 296);
  const float* x = nt + (size_t)node * 208;
  float va = 0.f;
  if (r < 32) va = x[r];
  else if (r < 160) { int q = r - 32;  int u = q >> 2, m = q & 3;  if (m < 3) va = x[32 + u * 3 + m]; }
  else if (r < 288) { int q = r - 160; int u = q >> 3, m = q & 7;  if (m < 5) va = x[128 + u * 5 + m]; }
  __half ha = __float2half(va);
  ta[(size_t)node * 296 + r] = *reinterpret_cast<uint16_t*>(&ha);
  if (r < 216) {
    float vb = 0.f;
    if (r < 32) vb = x[r];
    else if (r < 128) { int q = r - 32;  int m = q >> 5, v = q & 31; vb = x[32 + v * 3 + m]; }
    else if (r < 208) { int q = r - 128; int m = q >> 4, v = q & 15; vb = x[128 + v * 5 + m]; }
    __half hb = __float2half(vb);
    tb[(size_t)node * 216 + r] = *reinterpret_cast<uint16_t*>(&hb);
  }
}

__device__ __forceinline__ void gload16(const void* g, void* l) {
  __builtin_amdgcn_global_load_lds(
      (const __attribute__((address_space(1))) void*)g,
      (__attribute__((address_space(3))) void*)l, 16, 0, 0);
}

// W ring load: 4 x dwordx4 per lane from tile Tc. WRA is a uint4[4] array name.
#define LOADW(WRA, TEXPR)                                                       \
  { int Tc_ = (TEXPR);                                                          \
    _Pragma("unroll") for (int nf = 0; nf < 4; ++nf)                            \
      WRA[nf] = wtg4[Tc_ * 256 + nf * 64 + lo4]; }

#define MSTEPA(WRA, A)                                                          \
  _Pragma("unroll") for (int mf = 0; mf < 2; ++mf)                              \
  _Pragma("unroll") for (int nf = 0; nf < 4; ++nf)                              \
    acc[mf][nf] = __builtin_amdgcn_mfma_f32_16x16x32_f16(                       \
        (A)[mf], *(const f16x8*)&WRA[nf], acc[mf][nf], 0, 0, 0);

#define BUILD_S(T_, A)                                                          \
  _Pragma("unroll") for (int mf = 0; mf < 2; ++mf) {                            \
    __half s1v = *(const __half*)(x1b[mf] + 2 * (T_));                          \
    __half2 s1b2 = __half2half2(s1v);                                           \
    union { uint32_t u[4]; f16x8 v; } au_;                                      \
    _Pragma("unroll") for (int q = 0; q < 4; ++q) {                             \
      __half2 p = __hmul2(s1b2, ((const __half2*)&s2pk[mf])[q]);                \
      au_.u[q] = *(uint32_t*)&p;                                                \
    }                                                                           \
    (A)[mf] = au_.v;                                                            \
  }

#define BUILD_V(U_, A)                                                          \
  _Pragma("unroll") for (int mf = 0; mf < 2; ++mf) {                            \
    uint2 vv_ = *(const uint2*)(x1b[mf] + 64 + (U_) * 8);                       \
    __half2 h01_ = *(__half2*)&vv_.x;                                           \
    __half2 h2x_ = *(__half2*)&vv_.y;                                           \
    __half2 va0 = __half2half2(__low2half(h01_));                               \
    __half2 va1 = __half2half2(__high2half(h01_));                              \
    __half2 va2 = __half2half2(__low2half(h2x_));                               \
    union { uint32_t u[4]; f16x8 v; } au_;                                      \
    _Pragma("unroll") for (int q = 0; q < 4; ++q) {                             \
      __half2 p = __hmul2(va0, ((const __half2*)&v2pk[mf][0])[q]);              \
      p = __hfma2(va1, ((const __half2*)&v2pk[mf][1])[q], p);                   \
      p = __hfma2(va2, ((const __half2*)&v2pk[mf][2])[q], p);                   \
      au_.u[q] = *(uint32_t*)&p;                                                \
    }                                                                           \
    (A)[mf] = au_.v;                                                            \
  }

// T-phase: both mf rows in one pass (wave owns only 2 mf tiles now).
#define BUILD_T(TT_, A)                                                         \
  _Pragma("unroll") for (int mm = 0; mm < 2; ++mm) {                            \
    int u_ = (TT_) * 2 + (g >> 1);                                              \
    uint4 tv_ = *(const uint4*)(x1b[mm] + 320 + u_ * 16);                       \
    __half2 w01_ = *(__half2*)&tv_.x;                                           \
    __half2 w23_ = *(__half2*)&tv_.y;                                           \
    __half2 w4x_ = *(__half2*)&tv_.z;                                           \
    __half2 tb0 = __half2half2(__low2half(w01_));                               \
    __half2 tb1 = __half2half2(__high2half(w01_));                              \
    __half2 tb2 = __half2half2(__low2half(w23_));                               \
    __half2 tb3 = __half2half2(__high2half(w23_));                              \
    __half2 tb4 = __half2half2(__low2half(w4x_));                               \
    union { uint32_t u[4]; f16x8 v; } au_;                                      \
    _Pragma("unroll") for (int q = 0; q < 4; ++q) {                             \
      __half2 p = __hmul2(tb0, ((const __half2*)&t2pk[mm][0])[q]);              \
      p = __hfma2(tb1, ((const __half2*)&t2pk[mm][1])[q], p);                   \
      p = __hfma2(tb2, ((const __half2*)&t2pk[mm][2])[q], p);                   \
      p = __hfma2(tb3, ((const __half2*)&t2pk[mm][3])[q], p);                   \
      p = __hfma2(tb4, ((const __half2*)&t2pk[mm][4])[q], p);                   \
      au_.u[q] = *(uint32_t*)&p;                                                \
    }                                                                           \
    (A)[mm] = au_.v;                                                            \
  }

#define RING_S(WRA, P, T0) { f16x8 a[2]; BUILD_S((T0) + (P), a); MSTEPA(WRA, a); LOADW(WRA, (T0) + (P) + 4); }
#define RING_V(WRA, P, T0) { f16x8 a[2]; BUILD_V((T0) + (P) - 32, a); MSTEPA(WRA, a); LOADW(WRA, (T0) + (P) + 4); }
#define WRAPT(X) ((X) <= 71 ? (X) : (X) - 8)
#define RING_T(WRA, P, T0) { f16x8 a[2]; BUILD_T((T0) + (P) - 64, a); MSTEPA(WRA, a); LOADW(WRA, WRAPT((T0) + (P) + 4)); }

// LDS: x1 [128 rows][592 B] = 75776 B. Epilogue overlay:
//   etile f32 [2][128][68] @0 (69632 B) ; A1s f32 [2048] @69632 (8192 B). Total 77824.
// 77824*2 = 155648 <= 163840 -> 2 blocks/CU -> 4 waves/SIMD.
__global__ __launch_bounds__(NT, 4) void edge_main(
    const uint16_t* __restrict__ ta, const uint16_t* __restrict__ tbl,
    const int* __restrict__ ei, const uint16_t* __restrict__ wt,
    const float* __restrict__ A1, const float* __restrict__ b1,
    const float* __restrict__ A2, const float* __restrict__ b2,
    float* __restrict__ out)
{
  __shared__ alignas(16) unsigned char smem[77824];
  const int tid = threadIdx.x;
  const int e0 = blockIdx.x * BM;

  // ---- stage x1 via global_load_lds: 4736 16B chunks (128 rows x 37) ----
  {
    #pragma unroll
    for (int i = 0; i < 9; ++i) {
      unsigned idx = i * 512 + tid;
      unsigned row = idx / 37u;
      unsigned cj = idx - row * 37u;
      int e = e0 + (int)row; if (e > N_EDGES - 1) e = N_EDGES - 1;
      int src = ei[e];
      const char* gp = (const char*)ta + (size_t)src * 592 + cj * 16;
      void* lp = (void*)(smem + i * 8192 + (tid >> 6) * 1024);
      gload16(gp, lp);
    }
    if (tid < 128) {
      unsigned idx = 4608 + tid;
      unsigned row = idx / 37u;
      unsigned cj = idx - row * 37u;
      int e = e0 + (int)row; if (e > N_EDGES - 1) e = N_EDGES - 1;
      int src = ei[e];
      const char* gp = (const char*)ta + (size_t)src * 592 + cj * 16;
      void* lp = (void*)(smem + 73728 + (tid >> 6) * 1024);
      gload16(gp, lp);
    }
  }
  asm volatile("s_waitcnt vmcnt(0)" ::: "memory");
  __syncthreads();

  const int lane = tid & 63, c = lane & 15, g = lane >> 4;
  const int wv = tid >> 6;
  const int m = wv >> 1;     // M-quarter (32 edges)
  const int kh = wv & 1;     // K-half
  const int lo4 = c * 4 + g;

  const unsigned char* x1b[2];
  const unsigned char* tbp[2];
  #pragma unroll
  for (int mf = 0; mf < 2; ++mf) {
    int erow = m * 32 + mf * 16 + c;
    x1b[mf] = smem + (size_t)erow * 592;
    int e = e0 + erow; if (e > N_EDGES - 1) e = N_EDGES - 1;
    int dst = ei[N_EDGES + e];
    tbp[mf] = (const unsigned char*)tbl + (size_t)dst * 432;
  }

  f32x4 acc[2][4];
  #pragma unroll
  for (int mf = 0; mf < 2; ++mf)
    #pragma unroll
    for (int nf = 0; nf < 4; ++nf) acc[mf][nf] = (f32x4){0.f, 0.f, 0.f, 0.f};

  const uint4* wtg4 = (const uint4*)wt;
  uint4 wr0[4], wr1[4], wr2[4], wr3[4];   // 4-deep ring, literal-indexed

  if (kh == 0) {
    // ---- K-half 0: S tiles 0..31, V u=0..11 (tiles 32..43) ----
    uint4 s2pk[2];
    #pragma unroll
    for (int mf = 0; mf < 2; ++mf) s2pk[mf] = *(const uint4*)(tbp[mf] + g * 16);
    LOADW(wr0, 0); LOADW(wr1, 1); LOADW(wr2, 2); LOADW(wr3, 3);
    for (int T = 0; T < 32; T += 4) {
      RING_S(wr0, 0, T); RING_S(wr1, 1, T); RING_S(wr2, 2, T); RING_S(wr3, 3, T);
    }
    uint4 v2pk[2][3];
    #pragma unroll
    for (int mf = 0; mf < 2; ++mf)
      #pragma unroll
      for (int m3 = 0; m3 < 3; ++m3)
        v2pk[mf][m3] = *(const uint4*)(tbp[mf] + 64 + m3 * 64 + g * 16);
    for (int T = 32; T < 44; T += 4) {
      RING_V(wr0, 0, T); RING_V(wr1, 1, T); RING_V(wr2, 2, T); RING_V(wr3, 3, T);
    }
  } else {
    // ---- K-half 1: V u=12..31 (tiles 44..63), T tiles 64..71 single pass ----
    uint4 v2pk[2][3];
    #pragma unroll
    for (int mf = 0; mf < 2; ++mf)
      #pragma unroll
      for (int m3 = 0; m3 < 3; ++m3)
        v2pk[mf][m3] = *(const uint4*)(tbp[mf] + 64 + m3 * 64 + g * 16);
    LOADW(wr0, 44); LOADW(wr1, 45); LOADW(wr2, 46); LOADW(wr3, 47);
    for (int T = 44; T < 64; T += 4) {
      RING_V(wr0, 0, T); RING_V(wr1, 1, T); RING_V(wr2, 2, T); RING_V(wr3, 3, T);
    }
    {
      uint4 t2pk[2][5];
      #pragma unroll
      for (int mm = 0; mm < 2; ++mm)
        #pragma unroll
        for (int m5 = 0; m5 < 5; ++m5)
          t2pk[mm][m5] = *(const uint4*)(tbp[mm] + 256 + m5 * 32 + (g & 1) * 16);
      RING_T(wr0, 0, 64); RING_T(wr1, 1, 64); RING_T(wr2, 2, 64); RING_T(wr3, 3, 64);
      RING_T(wr0, 0, 68); RING_T(wr1, 1, 68); RING_T(wr2, 2, 68); RING_T(wr3, 3, 68);
    }
  }

  // ---- epilogue: all waves done -> overlay partial e-tiles on x1 ----
  __syncthreads();
  float* etile = (float*)smem;
  #pragma unroll
  for (int mf = 0; mf < 2; ++mf)
    #pragma unroll
    for (int nf = 0; nf < 4; ++nf)
      #pragma unroll
      for (int rr = 0; rr < 4; ++rr)
        etile[(size_t)(kh * 128 + m * 32 + mf * 16 + g * 4 + rr) * 68 + nf * 16 + c] =
            acc[mf][nf][rr];
  // stage A1 (8 KB) into LDS above etile
  {
    float4* d4 = (float4*)(smem + 69632);
    d4[tid] = ((const float4*)A1)[tid];
  }
  __syncthreads();

  // ---- MLP head: 2 threads/edge (j-halves of 16), threads 0..255 ----
  if (tid < 256) {
    int el = tid >> 1, jh = tid & 1;
    const float* er0 = etile + (size_t)el * 68;
    const float* er1 = etile + (size_t)(128 + el) * 68;
    const float* A1s = (const float*)(smem + 69632);
    float hacc[16];
    #pragma unroll
    for (int j = 0; j < 16; ++j) hacc[j] = b1[jh * 16 + j];
    for (int w4 = 0; w4 < 16; ++w4) {
      float4 ea = *(const float4*)(er0 + w4 * 4);
      float4 eb = *(const float4*)(er1 + w4 * 4);
      #pragma unroll
      for (int q2 = 0; q2 < 4; ++q2) {
        float ev = (&ea.x)[q2] + (&eb.x)[q2];
        int w = w4 * 4 + q2;
        float4 a0 = *(const float4*)(A1s + w * 32 + jh * 16);
        float4 a1 = *(const float4*)(A1s + w * 32 + jh * 16 + 4);
        float4 a2 = *(const float4*)(A1s + w * 32 + jh * 16 + 8);
        float4 a3 = *(const float4*)(A1s + w * 32 + jh * 16 + 12);
        hacc[0]  += ev * a0.x; hacc[1]  += ev * a0.y; hacc[2]  += ev * a0.z; hacc[3]  += ev * a0.w;
        hacc[4]  += ev * a1.x; hacc[5]  += ev * a1.y; hacc[6]  += ev * a1.z; hacc[7]  += ev * a1.w;
        hacc[8]  += ev * a2.x; hacc[9]  += ev * a2.y; hacc[10] += ev * a2.z; hacc[11] += ev * a2.w;
        hacc[12] += ev * a3.x; hacc[13] += ev * a3.y; hacc[14] += ev * a3.z; hacc[15] += ev * a3.w;
      }
    }
    float o = 0.f;
    #pragma unroll
    for (int j = 0; j < 16; ++j) {
      float z = hacc[j];
      o += (z / (1.f + __expf(-z))) * A2[jh * 16 + j];
    }
    o += __shfl_xor(o, 1);
    int e = e0 + el;
    if (jh == 0 && e < N_EDGES) out[e] = o + b2[0];
  }
}

extern "C" void kernel_launch(void* const* d_in, const int* in_sizes, int n_in,
                              void* d_out, int out_size, void* d_ws, size_t ws_size,
                              hipStream_t stream) {
  const float* nt = (const float*)d_in[0];
  const int*   ei = (const int*)d_in[1];
  const float* W0 = (const float*)d_in[2];
  const float* W1 = (const float*)d_in[3];
  const float* W2 = (const float*)d_in[4];
  const float* A1 = (const float*)d_in[5];
  const float* b1 = (const float*)d_in[6];
  const float* A2 = (const float*)d_in[7];
  const float* b2 = (const float*)d_in[8];
  float* out = (float*)d_out;

  // ws layout: wt 294912B | TA 50000*592 | TB 50000*432   (~51.5 MB total)
  uint16_t* wt = (uint16_t*)d_ws;
  uint16_t* ta = (uint16_t*)((char*)d_ws + 294912);
  uint16_t* tb = (uint16_t*)((char*)d_ws + 294912 + (size_t)N_NODES * 592);

  prep_w<<<576, 256, 0, stream>>>(W0, W1, W2, wt);
  {
    long long tot = (long long)N_NODES * 296;
    int blocks = (int)((tot + 255) / 256);
    prep_tables<<<blocks, 256, 0, stream>>>(nt, ta, tb);
  }
  edge_main<<<(N_EDGES + BM - 1) / BM, NT, 0, stream>>>(ta, tb, ei, wt, A1, b1, A2, b2, out);
}

// Round 2
// 202.221 us; speedup vs baseline: 1.2645x; 1.2645x over previous
//
#include <hip/hip_runtime.h>
#include <hip/hip_fp16.h>
#include <stdint.h>

#define N_EDGES 200000
#define N_NODES 50000
#define BM 128
#define NT 512

typedef _Float16 f16x8 __attribute__((ext_vector_type(8)));
typedef float f32x4 __attribute__((ext_vector_type(4)));

// ---- prep_w: W -> f16, scales folded. wt[T*2048 + w*32 + kk] = f16(scale*W[k=T*32+kk][w])
__global__ void prep_w(const float* __restrict__ W0, const float* __restrict__ W1,
                       const float* __restrict__ W2, uint16_t* __restrict__ wt) {
  int o = blockIdx.x * 256 + threadIdx.x;     // 147456 total
  int T = o >> 11, r = o & 2047, w = r >> 5, kk = r & 31;
  int k = T * 32 + kk;
  const float AS = 1.0f / 48.0f;                  // 1/sqrt(2304)
  const float AV = AS * 0.57735026918962576f;     // /sqrt(3)
  const float AT = AS * 0.44721359549995794f;     // /sqrt(5)
  float val;
  if (k < 1024)      val = AS * W0[(k >> 5) * 2048 + (k & 31) * 64 + w];
  else if (k < 2048) { int k2 = k - 1024; val = AV * W1[(k2 >> 5) * 2048 + (k2 & 31) * 64 + w]; }
  else               { int k2 = k - 2048; val = AT * W2[(k2 >> 4) * 1024 + (k2 & 15) * 64 + w]; }
  __half h = __float2half(val);
  wt[o] = *reinterpret_cast<uint16_t*>(&h);
}

// ---- prep_tables: node_tensors -> TA (u-major, 296 u16/row) + TB (m-major, 216 u16/row)
__global__ void prep_tables(const float* __restrict__ nt,
                            uint16_t* __restrict__ ta, uint16_t* __restrict__ tb) {
  long long o = (long long)blockIdx.x * 256 + threadIdx.x;
  if (o >= (long long)N_NODES * 296) return;
  int node = (int)(o / 296);
  int r = (int)(o - (long long)node * 296);
  const float* x = nt + (size_t)node * 208;
  float va = 0.f;
  if (r < 32) va = x[r];
  else if (r < 160) { int q = r - 32;  int u = q >> 2, m = q & 3;  if (m < 3) va = x[32 + u * 3 + m]; }
  else if (r < 288) { int q = r - 160; int u = q >> 3, m = q & 7;  if (m < 5) va = x[128 + u * 5 + m]; }
  __half ha = __float2half(va);
  ta[(size_t)node * 296 + r] = *reinterpret_cast<uint16_t*>(&ha);
  if (r < 216) {
    float vb = 0.f;
    if (r < 32) vb = x[r];
    else if (r < 128) { int q = r - 32;  int m = q >> 5, v = q & 31; vb = x[32 + v * 3 + m]; }
    else if (r < 208) { int q = r - 128; int m = q >> 4, v = q & 15; vb = x[128 + v * 5 + m]; }
    __half hb = __float2half(vb);
    tb[(size_t)node * 216 + r] = *reinterpret_cast<uint16_t*>(&hb);
  }
}

__device__ __forceinline__ void gload16(const void* g, void* l) {
  __builtin_amdgcn_global_load_lds(
      (const __attribute__((address_space(1))) void*)g,
      (__attribute__((address_space(3))) void*)l, 16, 0, 0);
}

// W ring load: 4 x dwordx4 per lane from tile Tc. WRA is a uint4[4] array name.
#define LOADW(WRA, TEXPR)                                                       \
  { int Tc_ = (TEXPR);                                                          \
    _Pragma("unroll") for (int nf = 0; nf < 4; ++nf)                            \
      WRA[nf] = wtg4[Tc_ * 256 + nf * 64 + lo4]; }

#define MSTEPA(WRA, A)                                                          \
  _Pragma("unroll") for (int mf = 0; mf < 2; ++mf)                              \
  _Pragma("unroll") for (int nf = 0; nf < 4; ++nf)                              \
    acc[mf][nf] = __builtin_amdgcn_mfma_f32_16x16x32_f16(                       \
        (A)[mf], *(const f16x8*)&WRA[nf], acc[mf][nf], 0, 0, 0);

#define BUILD_S(T_, A)                                                          \
  _Pragma("unroll") for (int mf = 0; mf < 2; ++mf) {                            \
    __half s1v = *(const __half*)(x1b[mf] + 2 * (T_));                          \
    __half2 s1b2 = __half2half2(s1v);                                           \
    union { uint32_t u[4]; f16x8 v; } au_;                                      \
    _Pragma("unroll") for (int q = 0; q < 4; ++q) {                             \
      __half2 p = __hmul2(s1b2, ((const __half2*)&s2pk[mf])[q]);                \
      au_.u[q] = *(uint32_t*)&p;                                                \
    }                                                                           \
    (A)[mf] = au_.v;                                                            \
  }

#define BUILD_V(U_, A)                                                          \
  _Pragma("unroll") for (int mf = 0; mf < 2; ++mf) {                            \
    uint2 vv_ = *(const uint2*)(x1b[mf] + 64 + (U_) * 8);                       \
    __half2 h01_ = *(__half2*)&vv_.x;                                           \
    __half2 h2x_ = *(__half2*)&vv_.y;                                           \
    __half2 va0 = __half2half2(__low2half(h01_));                               \
    __half2 va1 = __half2half2(__high2half(h01_));                              \
    __half2 va2 = __half2half2(__low2half(h2x_));                               \
    union { uint32_t u[4]; f16x8 v; } au_;                                      \
    _Pragma("unroll") for (int q = 0; q < 4; ++q) {                             \
      __half2 p = __hmul2(va0, ((const __half2*)&v2pk[mf][0])[q]);              \
      p = __hfma2(va1, ((const __half2*)&v2pk[mf][1])[q], p);                   \
      p = __hfma2(va2, ((const __half2*)&v2pk[mf][2])[q], p);                   \
      au_.u[q] = *(uint32_t*)&p;                                                \
    }                                                                           \
    (A)[mf] = au_.v;                                                            \
  }

// T-phase: both mf rows in one pass (wave owns only 2 mf tiles now).
#define BUILD_T(TT_, A)                                                         \
  _Pragma("unroll") for (int mm = 0; mm < 2; ++mm) {                            \
    int u_ = (TT_) * 2 + (g >> 1);                                              \
    uint4 tv_ = *(const uint4*)(x1b[mm] + 320 + u_ * 16);                       \
    __half2 w01_ = *(__half2*)&tv_.x;                                           \
    __half2 w23_ = *(__half2*)&tv_.y;                                           \
    __half2 w4x_ = *(__half2*)&tv_.z;                                           \
    __half2 tb0 = __half2half2(__low2half(w01_));                               \
    __half2 tb1 = __half2half2(__high2half(w01_));                              \
    __half2 tb2 = __half2half2(__low2half(w23_));                               \
    __half2 tb3 = __half2half2(__high2half(w23_));                              \
    __half2 tb4 = __half2half2(__low2half(w4x_));                               \
    union { uint32_t u[4]; f16x8 v; } au_;                                      \
    _Pragma("unroll") for (int q = 0; q < 4; ++q) {                             \
      __half2 p = __hmul2(tb0, ((const __half2*)&t2pk[mm][0])[q]);              \
      p = __hfma2(tb1, ((const __half2*)&t2pk[mm][1])[q], p);                   \
      p = __hfma2(tb2, ((const __half2*)&t2pk[mm][2])[q], p);                   \
      p = __hfma2(tb3, ((const __half2*)&t2pk[mm][3])[q], p);                   \
      p = __hfma2(tb4, ((const __half2*)&t2pk[mm][4])[q], p);                   \
      au_.u[q] = *(uint32_t*)&p;                                                \
    }                                                                           \
    (A)[mm] = au_.v;                                                            \
  }

#define RING_S(WRA, P, T0) { f16x8 a[2]; BUILD_S((T0) + (P), a); MSTEPA(WRA, a); LOADW(WRA, (T0) + (P) + 4); }
#define RING_V(WRA, P, T0) { f16x8 a[2]; BUILD_V((T0) + (P) - 32, a); MSTEPA(WRA, a); LOADW(WRA, (T0) + (P) + 4); }
#define WRAPT(X) ((X) <= 71 ? (X) : (X) - 8)
#define RING_T(WRA, P, T0) { f16x8 a[2]; BUILD_T((T0) + (P) - 64, a); MSTEPA(WRA, a); LOADW(WRA, WRAPT((T0) + (P) + 4)); }

// LDS: x1 [128 rows][592 B] = 75776 B. Epilogue overlay:
//   etile f32 [2][128][68] @0 (69632 B) ; A1s f32 [2048] @69632 (8192 B). Total 77824.
// 77824*2 = 155648 <= 163840 -> 2 blocks/CU by LDS.
// __launch_bounds__(512,2): empirically yields 128-VGPR cap (no spill).
// (512,4) forced 64 VGPRs -> 184 MB scratch spill traffic (round 1 post-mortem).
__global__ __launch_bounds__(NT, 2) void edge_main(
    const uint16_t* __restrict__ ta, const uint16_t* __restrict__ tbl,
    const int* __restrict__ ei, const uint16_t* __restrict__ wt,
    const float* __restrict__ A1, const float* __restrict__ b1,
    const float* __restrict__ A2, const float* __restrict__ b2,
    float* __restrict__ out)
{
  __shared__ alignas(16) unsigned char smem[77824];
  const int tid = threadIdx.x;
  const int e0 = blockIdx.x * BM;

  // ---- stage x1 via global_load_lds: 4736 16B chunks (128 rows x 37) ----
  {
    #pragma unroll
    for (int i = 0; i < 9; ++i) {
      unsigned idx = i * 512 + tid;
      unsigned row = idx / 37u;
      unsigned cj = idx - row * 37u;
      int e = e0 + (int)row; if (e > N_EDGES - 1) e = N_EDGES - 1;
      int src = ei[e];
      const char* gp = (const char*)ta + (size_t)src * 592 + cj * 16;
      void* lp = (void*)(smem + i * 8192 + (tid >> 6) * 1024);
      gload16(gp, lp);
    }
    if (tid < 128) {
      unsigned idx = 4608 + tid;
      unsigned row = idx / 37u;
      unsigned cj = idx - row * 37u;
      int e = e0 + (int)row; if (e > N_EDGES - 1) e = N_EDGES - 1;
      int src = ei[e];
      const char* gp = (const char*)ta + (size_t)src * 592 + cj * 16;
      void* lp = (void*)(smem + 73728 + (tid >> 6) * 1024);
      gload16(gp, lp);
    }
  }
  asm volatile("s_waitcnt vmcnt(0)" ::: "memory");
  __syncthreads();

  const int lane = tid & 63, c = lane & 15, g = lane >> 4;
  const int wv = tid >> 6;
  const int m = wv >> 1;     // M-quarter (32 edges)
  const int kh = wv & 1;     // K-half
  const int lo4 = c * 4 + g;

  const unsigned char* x1b[2];
  const unsigned char* tbp[2];
  #pragma unroll
  for (int mf = 0; mf < 2; ++mf) {
    int erow = m * 32 + mf * 16 + c;
    x1b[mf] = smem + (size_t)erow * 592;
    int e = e0 + erow; if (e > N_EDGES - 1) e = N_EDGES - 1;
    int dst = ei[N_EDGES + e];
    tbp[mf] = (const unsigned char*)tbl + (size_t)dst * 432;
  }

  f32x4 acc[2][4];
  #pragma unroll
  for (int mf = 0; mf < 2; ++mf)
    #pragma unroll
    for (int nf = 0; nf < 4; ++nf) acc[mf][nf] = (f32x4){0.f, 0.f, 0.f, 0.f};

  const uint4* wtg4 = (const uint4*)wt;
  uint4 wr0[4], wr1[4], wr2[4], wr3[4];   // 4-deep ring, literal-indexed

  if (kh == 0) {
    // ---- K-half 0: S tiles 0..31, V u=0..11 (tiles 32..43) ----
    uint4 s2pk[2];
    #pragma unroll
    for (int mf = 0; mf < 2; ++mf) s2pk[mf] = *(const uint4*)(tbp[mf] + g * 16);
    LOADW(wr0, 0); LOADW(wr1, 1); LOADW(wr2, 2); LOADW(wr3, 3);
    for (int T = 0; T < 32; T += 4) {
      RING_S(wr0, 0, T); RING_S(wr1, 1, T); RING_S(wr2, 2, T); RING_S(wr3, 3, T);
    }
    uint4 v2pk[2][3];
    #pragma unroll
    for (int mf = 0; mf < 2; ++mf)
      #pragma unroll
      for (int m3 = 0; m3 < 3; ++m3)
        v2pk[mf][m3] = *(const uint4*)(tbp[mf] + 64 + m3 * 64 + g * 16);
    for (int T = 32; T < 44; T += 4) {
      RING_V(wr0, 0, T); RING_V(wr1, 1, T); RING_V(wr2, 2, T); RING_V(wr3, 3, T);
    }
  } else {
    // ---- K-half 1: V u=12..31 (tiles 44..63), T tiles 64..71 single pass ----
    uint4 v2pk[2][3];
    #pragma unroll
    for (int mf = 0; mf < 2; ++mf)
      #pragma unroll
      for (int m3 = 0; m3 < 3; ++m3)
        v2pk[mf][m3] = *(const uint4*)(tbp[mf] + 64 + m3 * 64 + g * 16);
    LOADW(wr0, 44); LOADW(wr1, 45); LOADW(wr2, 46); LOADW(wr3, 47);
    for (int T = 44; T < 64; T += 4) {
      RING_V(wr0, 0, T); RING_V(wr1, 1, T); RING_V(wr2, 2, T); RING_V(wr3, 3, T);
    }
    {
      uint4 t2pk[2][5];
      #pragma unroll
      for (int mm = 0; mm < 2; ++mm)
        #pragma unroll
        for (int m5 = 0; m5 < 5; ++m5)
          t2pk[mm][m5] = *(const uint4*)(tbp[mm] + 256 + m5 * 32 + (g & 1) * 16);
      RING_T(wr0, 0, 64); RING_T(wr1, 1, 64); RING_T(wr2, 2, 64); RING_T(wr3, 3, 64);
      RING_T(wr0, 0, 68); RING_T(wr1, 1, 68); RING_T(wr2, 2, 68); RING_T(wr3, 3, 68);
    }
  }

  // ---- epilogue: all waves done -> overlay partial e-tiles on x1 ----
  __syncthreads();
  float* etile = (float*)smem;
  #pragma unroll
  for (int mf = 0; mf < 2; ++mf)
    #pragma unroll
    for (int nf = 0; nf < 4; ++nf)
      #pragma unroll
      for (int rr = 0; rr < 4; ++rr)
        etile[(size_t)(kh * 128 + m * 32 + mf * 16 + g * 4 + rr) * 68 + nf * 16 + c] =
            acc[mf][nf][rr];
  // stage A1 (8 KB) into LDS above etile
  {
    float4* d4 = (float4*)(smem + 69632);
    d4[tid] = ((const float4*)A1)[tid];
  }
  __syncthreads();

  // ---- MLP head: 2 threads/edge (j-halves of 16), threads 0..255 ----
  if (tid < 256) {
    int el = tid >> 1, jh = tid & 1;
    const float* er0 = etile + (size_t)el * 68;
    const float* er1 = etile + (size_t)(128 + el) * 68;
    const float* A1s = (const float*)(smem + 69632);
    float hacc[16];
    #pragma unroll
    for (int j = 0; j < 16; ++j) hacc[j] = b1[jh * 16 + j];
    for (int w4 = 0; w4 < 16; ++w4) {
      float4 ea = *(const float4*)(er0 + w4 * 4);
      float4 eb = *(const float4*)(er1 + w4 * 4);
      #pragma unroll
      for (int q2 = 0; q2 < 4; ++q2) {
        float ev = (&ea.x)[q2] + (&eb.x)[q2];
        int w = w4 * 4 + q2;
        float4 a0 = *(const float4*)(A1s + w * 32 + jh * 16);
        float4 a1 = *(const float4*)(A1s + w * 32 + jh * 16 + 4);
        float4 a2 = *(const float4*)(A1s + w * 32 + jh * 16 + 8);
        float4 a3 = *(const float4*)(A1s + w * 32 + jh * 16 + 12);
        hacc[0]  += ev * a0.x; hacc[1]  += ev * a0.y; hacc[2]  += ev * a0.z; hacc[3]  += ev * a0.w;
        hacc[4]  += ev * a1.x; hacc[5]  += ev * a1.y; hacc[6]  += ev * a1.z; hacc[7]  += ev * a1.w;
        hacc[8]  += ev * a2.x; hacc[9]  += ev * a2.y; hacc[10] += ev * a2.z; hacc[11] += ev * a2.w;
        hacc[12] += ev * a3.x; hacc[13] += ev * a3.y; hacc[14] += ev * a3.z; hacc[15] += ev * a3.w;
      }
    }
    float o = 0.f;
    #pragma unroll
    for (int j = 0; j < 16; ++j) {
      float z = hacc[j];
      o += (z / (1.f + __expf(-z))) * A2[jh * 16 + j];
    }
    o += __shfl_xor(o, 1);
    int e = e0 + el;
    if (jh == 0 && e < N_EDGES) out[e] = o + b2[0];
  }
}

extern "C" void kernel_launch(void* const* d_in, const int* in_sizes, int n_in,
                              void* d_out, int out_size, void* d_ws, size_t ws_size,
                              hipStream_t stream) {
  const float* nt = (const float*)d_in[0];
  const int*   ei = (const int*)d_in[1];
  const float* W0 = (const float*)d_in[2];
  const float* W1 = (const float*)d_in[3];
  const float* W2 = (const float*)d_in[4];
  const float* A1 = (const float*)d_in[5];
  const float* b1 = (const float*)d_in[6];
  const float* A2 = (const float*)d_in[7];
  const float* b2 = (const float*)d_in[8];
  float* out = (float*)d_out;

  // ws layout: wt 294912B | TA 50000*592 | TB 50000*432   (~51.5 MB total)
  uint16_t* wt = (uint16_t*)d_ws;
  uint16_t* ta = (uint16_t*)((char*)d_ws + 294912);
  uint16_t* tb = (uint16_t*)((char*)d_ws + 294912 + (size_t)N_NODES * 592);

  prep_w<<<576, 256, 0, stream>>>(W0, W1, W2, wt);
  {
    long long tot = (long long)N_NODES * 296;
    int blocks = (int)((tot + 255) / 256);
    prep_tables<<<blocks, 256, 0, stream>>>(nt, ta, tb);
  }
  edge_main<<<(N_EDGES + BM - 1) / BM, NT, 0, stream>>>(ta, tb, ei, wt, A1, b1, A2, b2, out);
}